// Round 7
// baseline (952.723 us; speedup 1.0000x reference)
//
#include <hip/hip_runtime.h>
#include <math.h>

#define Bn 8
#define Nn 256
#define Fn 32
#define NRBF 50
#define Hn 128
#define NK 255            // N-1 neighbors
#define ROW 8960          // N*(D+F)
#define EPSf 1e-6f
#define KP 64             // K padded 50 -> 64
#define L2E 1.44269504f
#define NPAIR 2048

typedef __attribute__((ext_vector_type(8))) __bf16 b8;
typedef __attribute__((ext_vector_type(4))) float f32x4;

__device__ __forceinline__ float fast_sig(float z) {
    return __builtin_amdgcn_rcpf(1.f + __builtin_amdgcn_exp2f(-z * L2E));
}

// ---------------------------------------------------------------------------
// Prep: pack Wb[g][h][k] bf16 (g: 0=s1_W1, 1=s1_W1*mu, 2=s2_W1, 3=f_W1;
// k>=50 zeroed) + zero the completion ticket. 128 blocks x 256 = 32768 elems.
// ---------------------------------------------------------------------------
__global__ __launch_bounds__(256) void prep_kernel(
    const float* __restrict__ s1_W1, const float* __restrict__ s2_W1,
    const float* __restrict__ f_W1,  const float* __restrict__ mus,
    __bf16* __restrict__ Wb, unsigned int* __restrict__ done)
{
    if (blockIdx.x == 0 && threadIdx.x == 0) *done = 0u;
    int idx = blockIdx.x * 256 + threadIdx.x;     // g*Hn*KP + h*KP + k
    int g = idx >> 13;
    int h = (idx >> 6) & 127;
    int k = idx & 63;
    float v = 0.f;
    if (k < NRBF) {
        if (g == 0)      v = s1_W1[k * Hn + h];
        else if (g == 1) v = s1_W1[k * Hn + h] * mus[k];
        else if (g == 2) v = s2_W1[k * Hn + h];
        else             v = f_W1[k * Hn + h];
    }
    Wb[idx] = (__bf16)v;
}

// ---------------------------------------------------------------------------
// One block (512 thr, 8 waves) per (b,i). Wave w owns rows [w*32, w*32+32).
// Wb staged in LDS (XOR chunk swizzle -> conflict-free ds_read_b128).
// z-arrays computed inline. Last-finishing block runs the finalize.
// ---------------------------------------------------------------------------
__global__ __launch_bounds__(512, 4) void pair_kernel(
    const float* __restrict__ state,
    const float* __restrict__ mus,   const float* __restrict__ gammap,
    const float* __restrict__ s1_W1, const float* __restrict__ s1_b1,
    const float* __restrict__ s1_W2, const float* __restrict__ s1_b2,
    const float* __restrict__ s2_W1, const float* __restrict__ s2_b1,
    const float* __restrict__ s2_W2, const float* __restrict__ s2_b2,
    const float* __restrict__ f_W1,  const float* __restrict__ f_b1,
    const float* __restrict__ f_W2,  const float* __restrict__ f_b2,
    const __bf16* __restrict__ Wb,
    float* __restrict__ vx_pre, float* __restrict__ tr_part,
    unsigned int* __restrict__ done,
    float* __restrict__ out)
{
    const int i = blockIdx.x, b = blockIdx.y;
    const int pi = b * Nn + i;
    const int tid  = threadIdx.x;
    const int w    = tid >> 6;        // wave 0..7
    const int lane = tid & 63;
    const int c    = lane & 15;       // A m-offset, B n, C/D col
    const int q    = lane >> 4;       // quad

    __shared__ __attribute__((aligned(16))) __bf16 WbL[4 * Hn * KP]; // 64 KiB
    __shared__ float xpos[Nn * 3];
    __shared__ float musS[64];
    __shared__ float ff[Fn], sf[Fn];
    __shared__ float zf1s[Hn], zf2s[Hn], zffs[Hn];
    __shared__ float sW2a[Hn], sW2b[Hn];
    __shared__ float afsumsh[Hn];
    __shared__ float accum7[8];
    __shared__ float fpart[8][33];
    __shared__ unsigned int lastflag;

    // ---- phase 1: stage everything; wave-7 shuffle softmax ----
    for (int t = tid; t < Nn * 3; t += 512) xpos[t] = state[b * ROW + t];
    {
        const b8* Wg = (const b8*)Wb;
        #pragma unroll
        for (int s = 0; s < 8; s++) {
            int lidx = tid + s * 512;                 // logical 16B-chunk id
            b8 v = Wg[lidx];
            int hh = (lidx >> 3) & 127;
            int pidx = (lidx & ~7) | ((lidx & 7) ^ (hh & 7));
            *(b8*)&WbL[pidx * 8] = v;
        }
    }
    if (tid < 64)  musS[tid] = (tid < NRBF) ? mus[tid] : 0.f;
    if (tid < Hn) { sW2a[tid] = s1_W2[tid]; sW2b[tid] = s2_W2[tid]; afsumsh[tid] = 0.f; }
    if (tid < 8)   accum7[tid] = 0.f;
    if (tid >= 448 && tid < 480) {                    // wave 7, lanes 0..31
        int l = tid - 448;
        float v = state[b * ROW + Nn * 3 + i * Fn + l];
        ff[l] = v;
        float mx = v;
        #pragma unroll
        for (int off = 16; off; off >>= 1) mx = fmaxf(mx, __shfl_xor(mx, off, 32));
        float e = __builtin_amdgcn_exp2f((v - mx) * L2E);
        float s = e;
        #pragma unroll
        for (int off = 16; off; off >>= 1) s += __shfl_xor(s, off, 32);
        sf[l] = e * __builtin_amdgcn_rcpf(s);
    }
    __syncthreads();                                   // S1

    const float gamma = gammap[0];
    const float ngl   = -gamma * L2E;
    const int   row0  = w * 32;
    const float xi0 = xpos[i * 3 + 0], xi1 = xpos[i * 3 + 1], xi2 = xpos[i * 3 + 2];

    // ---- phase 2a: A-fragments straight into registers ----
    b8 a0[2], a1[2];
    #pragma unroll
    for (int mc = 0; mc < 2; mc++) {
        int row = row0 + mc * 16 + c;
        int kk  = (row < NK) ? row : 0;               // row 255 dup of row 0; never read
        int j = kk + (kk >= i ? 1 : 0);
        float rx = xi0 - xpos[j * 3 + 0];
        float ry = xi1 - xpos[j * 3 + 1];
        float rz = xi2 - xpos[j * 3 + 2];
        float ssq = rx * rx + ry * ry + rz * rz;
        float dd  = sqrtf(ssq + EPSf);
        #pragma unroll
        for (int jj = 0; jj < 8; jj++) {
            float t = dd - musS[q * 8 + jj];
            a0[mc][jj] = (__bf16)__builtin_amdgcn_exp2f(ngl * t * t);
        }
        #pragma unroll
        for (int jj = 0; jj < 8; jj++) {              // k>=50 hits zero Wb rows
            float t = dd - musS[32 + q * 8 + jj];
            a1[mc][jj] = (__bf16)__builtin_amdgcn_exp2f(ngl * t * t);
        }
    }

    // ---- phase 2b: inline k-independent layer-1 halves ----
    if (tid < Hn) {
        int h = tid;
        float z1 = s1_b1[h], z2 = s2_b1[h];
        for (int f = 0; f < Fn; f++) {
            float fv = ff[f];
            z1 += fv * (s1_W1[(NRBF + f) * Hn + h] + s1_W1[(NRBF + Fn + f) * Hn + h]);
            z2 += fv * (s2_W1[(NRBF + f) * Hn + h] + s2_W1[(NRBF + Fn + f) * Hn + h]);
        }
        zf1s[h] = z1; zf2s[h] = z2;
    } else if (tid < 2 * Hn) {
        int h = tid - Hn;
        float zf = f_b1[h];
        for (int f = 0; f < Fn; f++)
            zf += sf[f] * f_W1[(NRBF + f) * Hn + h];
        zffs[h] = zf;
    }
    __syncthreads();                                   // S2

    // swizzled B-frag fetch: h&7 == c&7 since h = nt*16+c
    #define LDB(g, h, kq) (*(const b8*)&WbL[((((g) * Hn + (h)) << 3) | ((kq) ^ ((h) & 7))) * 8])

    float s1p[8], ds1a[8], ds1b[8], s2p[8];
    #pragma unroll
    for (int t = 0; t < 8; t++) { s1p[t] = 0.f; ds1a[t] = 0.f; ds1b[t] = 0.f; s2p[t] = 0.f; }

    // ---- pass 1: s1 + split derivative ----
    for (int nt = 0; nt < 8; nt++) {
        int h = nt * 16 + c;
        b8 b00 = LDB(0, h, q), b01 = LDB(0, h, 4 + q);
        b8 b10 = LDB(1, h, q), b11 = LDB(1, h, 4 + q);
        float w2  = sW2a[h];
        float zf1 = zf1s[h];
        #pragma unroll
        for (int mc = 0; mc < 2; mc++) {
            f32x4 acc1 = {0.f, 0.f, 0.f, 0.f}, accm = {0.f, 0.f, 0.f, 0.f};
            acc1 = __builtin_amdgcn_mfma_f32_16x16x32_bf16(a0[mc], b00, acc1, 0, 0, 0);
            acc1 = __builtin_amdgcn_mfma_f32_16x16x32_bf16(a1[mc], b01, acc1, 0, 0, 0);
            accm = __builtin_amdgcn_mfma_f32_16x16x32_bf16(a0[mc], b10, accm, 0, 0, 0);
            accm = __builtin_amdgcn_mfma_f32_16x16x32_bf16(a1[mc], b11, accm, 0, 0, 0);
            #pragma unroll
            for (int r = 0; r < 4; r++) {
                int idx = mc * 4 + r;
                float zr1 = acc1[r];
                float z1  = zr1 + zf1;
                float sig = fast_sig(z1);
                s1p[idx]  = fmaf(z1 * sig, w2, s1p[idx]);
                float cc  = w2 * (sig * fmaf(z1, 1.f - sig, 1.f));
                ds1a[idx] = fmaf(cc, zr1, ds1a[idx]);
                ds1b[idx] = fmaf(cc, accm[r], ds1b[idx]);
            }
        }
    }

    // ---- pass 2: s2 ----
    for (int nt = 0; nt < 8; nt++) {
        int h = nt * 16 + c;
        b8 b20 = LDB(2, h, q), b21 = LDB(2, h, 4 + q);
        float w2  = sW2b[h];
        float zf2 = zf2s[h];
        #pragma unroll
        for (int mc = 0; mc < 2; mc++) {
            f32x4 acc = {0.f, 0.f, 0.f, 0.f};
            acc = __builtin_amdgcn_mfma_f32_16x16x32_bf16(a0[mc], b20, acc, 0, 0, 0);
            acc = __builtin_amdgcn_mfma_f32_16x16x32_bf16(a1[mc], b21, acc, 0, 0, 0);
            #pragma unroll
            for (int r = 0; r < 4; r++) {
                int idx = mc * 4 + r;
                float z2 = acc[r] + zf2;
                s2p[idx] = fmaf(z2 * fast_sig(z2), w2, s2p[idx]);
            }
        }
    }

    // ---- pass 3: f MLP hidden, reduce over rows ----
    for (int nt = 0; nt < 8; nt++) {
        int h = nt * 16 + c;
        b8 b30 = LDB(3, h, q), b31 = LDB(3, h, 4 + q);
        float zff = zffs[h];
        float afp = 0.f;
        #pragma unroll
        for (int mc = 0; mc < 2; mc++) {
            f32x4 acc = {0.f, 0.f, 0.f, 0.f};
            acc = __builtin_amdgcn_mfma_f32_16x16x32_bf16(a0[mc], b30, acc, 0, 0, 0);
            acc = __builtin_amdgcn_mfma_f32_16x16x32_bf16(a1[mc], b31, acc, 0, 0, 0);
            #pragma unroll
            for (int r = 0; r < 4; r++) {
                int row = row0 + mc * 16 + q * 4 + r;
                float z  = acc[r] + zff;
                float av = z * fast_sig(z);
                afp += (row < NK) ? av : 0.f;
            }
        }
        afp += __shfl_xor(afp, 16, 64);
        afp += __shfl_xor(afp, 32, 64);
        if (lane < 16) atomicAdd(&afsumsh[h], afp);
    }

    // ---- distributive fold over this wave's 8 rows/lane ----
    {
        const float b2_1 = (c == 0) ? s1_b2[0] : 0.f;
        const float b2_2 = (c == 0) ? s2_b2[0] : 0.f;
        const float n2g  = -2.f * gamma;
        float p0 = 0.f, p1 = 0.f, p2 = 0.f, p3 = 0.f, p4 = 0.f, p5 = 0.f, p6 = 0.f;
        #pragma unroll
        for (int mc = 0; mc < 2; mc++)
            #pragma unroll
            for (int r = 0; r < 4; r++) {
                int idx = mc * 4 + r;
                int row = row0 + mc * 16 + q * 4 + r;
                if (row < NK) {
                    int j = row + (row >= i ? 1 : 0);
                    float rx = xi0 - xpos[j * 3 + 0];
                    float ry = xi1 - xpos[j * 3 + 1];
                    float rz = xi2 - xpos[j * 3 + 2];
                    float ssq = rx * rx + ry * ry + rz * rz;
                    float se  = ssq + EPSf;
                    float it  = __builtin_amdgcn_rsqf(se);
                    float dd  = se * it;
                    float e1  = s1p[idx] + b2_1;
                    float e2  = s2p[idx] + b2_2;
                    float e3  = fmaf(dd, ds1a[idx], -ds1b[idx]);
                    float fr  = n2g * ssq * it;
                    p0 = fmaf(rx, e1, p0); p1 = fmaf(ry, e1, p1); p2 = fmaf(rz, e1, p2);
                    p3 = fmaf(rx, e2, p3); p4 = fmaf(ry, e2, p4); p5 = fmaf(rz, e2, p5);
                    p6 = fmaf(fr, e3, fmaf(3.f, e1, p6));
                }
            }
        float ps[7] = {p0, p1, p2, p3, p4, p5, p6};
        #pragma unroll
        for (int off = 1; off < 64; off <<= 1)
            #pragma unroll
            for (int t = 0; t < 7; t++) ps[t] += __shfl_xor(ps[t], off, 64);
        if (lane == 0) {
            #pragma unroll
            for (int t = 0; t < 7; t++) atomicAdd(&accum7[t], ps[t]);
        }
    }
    __syncthreads();                                   // S3

    if (tid == 0) {
        const float inv = 1.f / 255.f;
        float vx0 = accum7[0] * inv, vx1 = accum7[1] * inv, vx2 = accum7[2] * inv;
        float cx = (accum7[4] * vx2 - accum7[5] * vx1) * inv;
        float cy = (accum7[5] * vx0 - accum7[3] * vx2) * inv;
        float cz = (accum7[3] * vx1 - accum7[4] * vx0) * inv;
        vx_pre[pi * 4 + 0] = vx0 + cx;
        vx_pre[pi * 4 + 1] = vx1 + cy;
        vx_pre[pi * 4 + 2] = vx2 + cz;
        tr_part[pi] = accum7[6];
    }
    if (tid < 256) {                                   // parallel f second layer
        int f = tid & 31, hg = tid >> 5;
        float p = 0.f;
        #pragma unroll
        for (int t = 0; t < 16; t++) {
            int h = hg * 16 + t;
            p = fmaf(afsumsh[h], f_W2[h * Fn + f], p);
        }
        fpart[hg][f] = p;
    }
    __syncthreads();                                   // S4
    if (tid < Fn) {
        float acc = 0.f;
        #pragma unroll
        for (int g = 0; g < 8; g++) acc += fpart[g][tid];
        out[b * ROW + Nn * 3 + i * Fn + tid] = fmaf(acc, 1.f / 255.f, f_b2[tid]);
    }

    // ---- last-block finalize (remove_mean + trace) ----
    __threadfence();
    __syncthreads();                                   // S5
    if (tid == 0) {
        unsigned int t = atomicAdd(done, 1u);
        lastflag = (t == NPAIR - 1) ? 1u : 0u;
    }
    __syncthreads();                                   // S6
    if (lastflag) {
        __threadfence();
        int bb = w;                                    // wave <-> batch
        float s0 = 0.f, s1 = 0.f, s2 = 0.f, s3 = 0.f;
        for (int ii = lane; ii < Nn; ii += 64) {
            int p = bb * Nn + ii;
            s0 += vx_pre[p * 4 + 0];
            s1 += vx_pre[p * 4 + 1];
            s2 += vx_pre[p * 4 + 2];
            s3 += tr_part[p];
        }
        #pragma unroll
        for (int off = 1; off < 64; off <<= 1) {
            s0 += __shfl_xor(s0, off, 64);
            s1 += __shfl_xor(s1, off, 64);
            s2 += __shfl_xor(s2, off, 64);
            s3 += __shfl_xor(s3, off, 64);
        }
        float m0 = s0 * (1.f / 256.f), m1 = s1 * (1.f / 256.f), m2 = s2 * (1.f / 256.f);
        for (int ii = lane; ii < Nn; ii += 64) {
            int p = bb * Nn + ii;
            out[bb * ROW + ii * 3 + 0] = vx_pre[p * 4 + 0] - m0;
            out[bb * ROW + ii * 3 + 1] = vx_pre[p * 4 + 1] - m1;
            out[bb * ROW + ii * 3 + 2] = vx_pre[p * 4 + 2] - m2;
        }
        if (lane == 0) out[Bn * ROW + bb] = s3 * (1.f / 255.f);
    }
}

// ---------------------------------------------------------------------------
extern "C" void kernel_launch(void* const* d_in, const int* in_sizes, int n_in,
                              void* d_out, int out_size, void* d_ws, size_t ws_size,
                              hipStream_t stream)
{
    const float* state = (const float*)d_in[1];
    const float* mus   = (const float*)d_in[2];
    const float* gam   = (const float*)d_in[3];
    const float* s1_W1 = (const float*)d_in[4];
    const float* s1_b1 = (const float*)d_in[5];
    const float* s1_W2 = (const float*)d_in[6];
    const float* s1_b2 = (const float*)d_in[7];
    const float* s2_W1 = (const float*)d_in[8];
    const float* s2_b1 = (const float*)d_in[9];
    const float* s2_W2 = (const float*)d_in[10];
    const float* s2_b2 = (const float*)d_in[11];
    const float* f_W1  = (const float*)d_in[12];
    const float* f_b1  = (const float*)d_in[13];
    const float* f_W2  = (const float*)d_in[14];
    const float* f_b2  = (const float*)d_in[15];

    char* wsb = (char*)d_ws;
    __bf16* Wb     = (__bf16*)wsb;                     // 65,536 B
    float*  vx_pre = (float*)(wsb + 65536);            // 32,768 B
    float*  tr_part = vx_pre + NPAIR * 4;              //  8,192 B
    unsigned int* done = (unsigned int*)(wsb + 65536 + 32768 + 8192);
    float*  out    = (float*)d_out;

    prep_kernel<<<128, 256, 0, stream>>>(s1_W1, s2_W1, f_W1, mus, Wb, done);

    dim3 grid(Nn, Bn);
    pair_kernel<<<grid, 512, 0, stream>>>(state, mus, gam,
        s1_W1, s1_b1, s1_W2, s1_b2,
        s2_W1, s2_b1, s2_W2, s2_b2,
        f_W1, f_b1, f_W2, f_b2,
        Wb, vx_pre, tr_part, done, out);
}

// Round 8
// 483.209 us; speedup vs baseline: 1.9717x; 1.9717x over previous
//
#include <hip/hip_runtime.h>
#include <math.h>

#define Bn 8
#define Nn 256
#define Fn 32
#define NRBF 50
#define Hn 128
#define NK 255            // N-1 neighbors
#define ROW 8960          // N*(D+F)
#define EPSf 1e-6f
#define KP 64             // K padded 50 -> 64
#define L2E 1.44269504f
#define NPAIR 2048

typedef __attribute__((ext_vector_type(8))) __bf16 b8;
typedef __attribute__((ext_vector_type(4))) float f32x4;

__device__ __forceinline__ float fast_sig(float z) {
    return __builtin_amdgcn_rcpf(1.f + __builtin_amdgcn_exp2f(-z * L2E));
}

// ---------------------------------------------------------------------------
// Prep: pack Wb[g][h][k] bf16 (g: 0=s1_W1, 1=s1_W1*mu, 2=s2_W1, 3=f_W1;
// k>=50 zeroed) + zero the completion ticket. 128 blocks x 256 = 32768 elems.
// ---------------------------------------------------------------------------
__global__ __launch_bounds__(256) void prep_kernel(
    const float* __restrict__ s1_W1, const float* __restrict__ s2_W1,
    const float* __restrict__ f_W1,  const float* __restrict__ mus,
    __bf16* __restrict__ Wb, unsigned int* __restrict__ done)
{
    if (blockIdx.x == 0 && threadIdx.x == 0) *done = 0u;
    int idx = blockIdx.x * 256 + threadIdx.x;     // g*Hn*KP + h*KP + k
    int g = idx >> 13;
    int h = (idx >> 6) & 127;
    int k = idx & 63;
    float v = 0.f;
    if (k < NRBF) {
        if (g == 0)      v = s1_W1[k * Hn + h];
        else if (g == 1) v = s1_W1[k * Hn + h] * mus[k];
        else if (g == 2) v = s2_W1[k * Hn + h];
        else             v = f_W1[k * Hn + h];
    }
    Wb[idx] = (__bf16)v;
}

// ---------------------------------------------------------------------------
// One block (512 thr, 8 waves) per (b,i). Wave w owns rows [w*32, w*32+32).
// Wb staged in LDS (XOR chunk swizzle -> conflict-free ds_read_b128).
// __launch_bounds__(512,2): gfx950 unified VGPR+AGPR file — waves/EU>2 caps
// the budget at 128 total and spills every accumulator (R4, R7: 500MB-1.4GB
// scratch traffic). LDS 73.7KB already limits to 2 blocks/CU.
// ---------------------------------------------------------------------------
__global__ __launch_bounds__(512, 2) void pair_kernel(
    const float* __restrict__ state,
    const float* __restrict__ mus,   const float* __restrict__ gammap,
    const float* __restrict__ s1_W1, const float* __restrict__ s1_b1,
    const float* __restrict__ s1_W2, const float* __restrict__ s1_b2,
    const float* __restrict__ s2_W1, const float* __restrict__ s2_b1,
    const float* __restrict__ s2_W2, const float* __restrict__ s2_b2,
    const float* __restrict__ f_W1,  const float* __restrict__ f_b1,
    const float* __restrict__ f_W2,  const float* __restrict__ f_b2,
    const __bf16* __restrict__ Wb,
    float* __restrict__ vx_pre, float* __restrict__ tr_part,
    unsigned int* __restrict__ done,
    float* __restrict__ out)
{
    const int i = blockIdx.x, b = blockIdx.y;
    const int pi = b * Nn + i;
    const int tid  = threadIdx.x;
    const int w    = tid >> 6;        // wave 0..7
    const int lane = tid & 63;
    const int c    = lane & 15;       // A m-offset, B n, C/D col
    const int q    = lane >> 4;       // quad

    __shared__ __attribute__((aligned(16))) __bf16 WbL[4 * Hn * KP]; // 64 KiB
    __shared__ float xpos[Nn * 3];
    __shared__ float musS[64];
    __shared__ float ff[Fn], sf[Fn];
    __shared__ float zf1s[Hn], zf2s[Hn], zffs[Hn];
    __shared__ float sW2a[Hn], sW2b[Hn];
    __shared__ float afsumsh[Hn];
    __shared__ float accum7[8];
    __shared__ float fpart[8][33];
    __shared__ unsigned int lastflag;

    // ---- phase 1: stage everything; wave-7 shuffle softmax ----
    for (int t = tid; t < Nn * 3; t += 512) xpos[t] = state[b * ROW + t];
    {
        const b8* Wg = (const b8*)Wb;
        #pragma unroll
        for (int s = 0; s < 8; s++) {
            int lidx = tid + s * 512;                 // logical 16B-chunk id
            b8 v = Wg[lidx];
            int hh = (lidx >> 3) & 127;
            int pidx = (lidx & ~7) | ((lidx & 7) ^ (hh & 7));
            *(b8*)&WbL[pidx * 8] = v;
        }
    }
    if (tid < 64)  musS[tid] = (tid < NRBF) ? mus[tid] : 0.f;
    if (tid < Hn) { sW2a[tid] = s1_W2[tid]; sW2b[tid] = s2_W2[tid]; afsumsh[tid] = 0.f; }
    if (tid < 8)   accum7[tid] = 0.f;
    if (tid >= 448 && tid < 480) {                    // wave 7, lanes 0..31
        int l = tid - 448;
        float v = state[b * ROW + Nn * 3 + i * Fn + l];
        ff[l] = v;
        float mx = v;
        #pragma unroll
        for (int off = 16; off; off >>= 1) mx = fmaxf(mx, __shfl_xor(mx, off, 32));
        float e = __builtin_amdgcn_exp2f((v - mx) * L2E);
        float s = e;
        #pragma unroll
        for (int off = 16; off; off >>= 1) s += __shfl_xor(s, off, 32);
        sf[l] = e * __builtin_amdgcn_rcpf(s);
    }
    __syncthreads();                                   // S1

    const float gamma = gammap[0];
    const float ngl   = -gamma * L2E;
    const int   row0  = w * 32;
    const float xi0 = xpos[i * 3 + 0], xi1 = xpos[i * 3 + 1], xi2 = xpos[i * 3 + 2];

    // ---- phase 2a: A-fragments straight into registers ----
    b8 a0[2], a1[2];
    #pragma unroll
    for (int mc = 0; mc < 2; mc++) {
        int row = row0 + mc * 16 + c;
        int kk  = (row < NK) ? row : 0;               // row 255: dup values, C row masked later
        int j = kk + (kk >= i ? 1 : 0);
        float rx = xi0 - xpos[j * 3 + 0];
        float ry = xi1 - xpos[j * 3 + 1];
        float rz = xi2 - xpos[j * 3 + 2];
        float ssq = rx * rx + ry * ry + rz * rz;
        float dd  = sqrtf(ssq + EPSf);
        #pragma unroll
        for (int jj = 0; jj < 8; jj++) {
            float t = dd - musS[q * 8 + jj];
            a0[mc][jj] = (__bf16)__builtin_amdgcn_exp2f(ngl * t * t);
        }
        #pragma unroll
        for (int jj = 0; jj < 8; jj++) {              // k>=50 hits zero Wb rows
            float t = dd - musS[32 + q * 8 + jj];
            a1[mc][jj] = (__bf16)__builtin_amdgcn_exp2f(ngl * t * t);
        }
    }

    // ---- phase 2b: inline k-independent layer-1 halves ----
    if (tid < Hn) {
        int h = tid;
        float z1 = s1_b1[h], z2 = s2_b1[h];
        for (int f = 0; f < Fn; f++) {
            float fv = ff[f];
            z1 += fv * (s1_W1[(NRBF + f) * Hn + h] + s1_W1[(NRBF + Fn + f) * Hn + h]);
            z2 += fv * (s2_W1[(NRBF + f) * Hn + h] + s2_W1[(NRBF + Fn + f) * Hn + h]);
        }
        zf1s[h] = z1; zf2s[h] = z2;
    } else if (tid < 2 * Hn) {
        int h = tid - Hn;
        float zf = f_b1[h];
        for (int f = 0; f < Fn; f++)
            zf += sf[f] * f_W1[(NRBF + f) * Hn + h];
        zffs[h] = zf;
    }
    __syncthreads();                                   // S2

    // swizzled B-frag fetch: conflict-free ds_read_b128
    #define LDB(g, h, kq) (*(const b8*)&WbL[((((g) * Hn + (h)) << 3) | ((kq) ^ ((h) & 7))) * 8])

    float s1p[8], ds1a[8], ds1b[8], s2p[8];
    #pragma unroll
    for (int t = 0; t < 8; t++) { s1p[t] = 0.f; ds1a[t] = 0.f; ds1b[t] = 0.f; s2p[t] = 0.f; }

    // ---- pass 1: s1 + split derivative ----
    for (int nt = 0; nt < 8; nt++) {
        int h = nt * 16 + c;
        b8 b00 = LDB(0, h, q), b01 = LDB(0, h, 4 + q);
        b8 b10 = LDB(1, h, q), b11 = LDB(1, h, 4 + q);
        float w2  = sW2a[h];
        float zf1 = zf1s[h];
        #pragma unroll
        for (int mc = 0; mc < 2; mc++) {
            f32x4 acc1 = {0.f, 0.f, 0.f, 0.f}, accm = {0.f, 0.f, 0.f, 0.f};
            acc1 = __builtin_amdgcn_mfma_f32_16x16x32_bf16(a0[mc], b00, acc1, 0, 0, 0);
            acc1 = __builtin_amdgcn_mfma_f32_16x16x32_bf16(a1[mc], b01, acc1, 0, 0, 0);
            accm = __builtin_amdgcn_mfma_f32_16x16x32_bf16(a0[mc], b10, accm, 0, 0, 0);
            accm = __builtin_amdgcn_mfma_f32_16x16x32_bf16(a1[mc], b11, accm, 0, 0, 0);
            #pragma unroll
            for (int r = 0; r < 4; r++) {
                int idx = mc * 4 + r;
                float zr1 = acc1[r];
                float z1  = zr1 + zf1;
                float sig = fast_sig(z1);
                s1p[idx]  = fmaf(z1 * sig, w2, s1p[idx]);
                float cc  = w2 * (sig * fmaf(z1, 1.f - sig, 1.f));
                ds1a[idx] = fmaf(cc, zr1, ds1a[idx]);
                ds1b[idx] = fmaf(cc, accm[r], ds1b[idx]);
            }
        }
    }

    // ---- pass 2: s2 ----
    for (int nt = 0; nt < 8; nt++) {
        int h = nt * 16 + c;
        b8 b20 = LDB(2, h, q), b21 = LDB(2, h, 4 + q);
        float w2  = sW2b[h];
        float zf2 = zf2s[h];
        #pragma unroll
        for (int mc = 0; mc < 2; mc++) {
            f32x4 acc = {0.f, 0.f, 0.f, 0.f};
            acc = __builtin_amdgcn_mfma_f32_16x16x32_bf16(a0[mc], b20, acc, 0, 0, 0);
            acc = __builtin_amdgcn_mfma_f32_16x16x32_bf16(a1[mc], b21, acc, 0, 0, 0);
            #pragma unroll
            for (int r = 0; r < 4; r++) {
                int idx = mc * 4 + r;
                float z2 = acc[r] + zf2;
                s2p[idx] = fmaf(z2 * fast_sig(z2), w2, s2p[idx]);
            }
        }
    }

    // ---- pass 3: f MLP hidden, reduce over rows ----
    for (int nt = 0; nt < 8; nt++) {
        int h = nt * 16 + c;
        b8 b30 = LDB(3, h, q), b31 = LDB(3, h, 4 + q);
        float zff = zffs[h];
        float afp = 0.f;
        #pragma unroll
        for (int mc = 0; mc < 2; mc++) {
            f32x4 acc = {0.f, 0.f, 0.f, 0.f};
            acc = __builtin_amdgcn_mfma_f32_16x16x32_bf16(a0[mc], b30, acc, 0, 0, 0);
            acc = __builtin_amdgcn_mfma_f32_16x16x32_bf16(a1[mc], b31, acc, 0, 0, 0);
            #pragma unroll
            for (int r = 0; r < 4; r++) {
                int row = row0 + mc * 16 + q * 4 + r;
                float z  = acc[r] + zff;
                float av = z * fast_sig(z);
                afp += (row < NK) ? av : 0.f;
            }
        }
        afp += __shfl_xor(afp, 16, 64);
        afp += __shfl_xor(afp, 32, 64);
        if (lane < 16) atomicAdd(&afsumsh[h], afp);
    }

    // ---- distributive fold over this wave's 8 rows/lane ----
    {
        const float b2_1 = (c == 0) ? s1_b2[0] : 0.f;
        const float b2_2 = (c == 0) ? s2_b2[0] : 0.f;
        const float n2g  = -2.f * gamma;
        float p0 = 0.f, p1 = 0.f, p2 = 0.f, p3 = 0.f, p4 = 0.f, p5 = 0.f, p6 = 0.f;
        #pragma unroll
        for (int mc = 0; mc < 2; mc++)
            #pragma unroll
            for (int r = 0; r < 4; r++) {
                int idx = mc * 4 + r;
                int row = row0 + mc * 16 + q * 4 + r;
                if (row < NK) {
                    int j = row + (row >= i ? 1 : 0);
                    float rx = xi0 - xpos[j * 3 + 0];
                    float ry = xi1 - xpos[j * 3 + 1];
                    float rz = xi2 - xpos[j * 3 + 2];
                    float ssq = rx * rx + ry * ry + rz * rz;
                    float se  = ssq + EPSf;
                    float it  = __builtin_amdgcn_rsqf(se);
                    float dd  = se * it;
                    float e1  = s1p[idx] + b2_1;
                    float e2  = s2p[idx] + b2_2;
                    float e3  = fmaf(dd, ds1a[idx], -ds1b[idx]);
                    float fr  = n2g * ssq * it;
                    p0 = fmaf(rx, e1, p0); p1 = fmaf(ry, e1, p1); p2 = fmaf(rz, e1, p2);
                    p3 = fmaf(rx, e2, p3); p4 = fmaf(ry, e2, p4); p5 = fmaf(rz, e2, p5);
                    p6 = fmaf(fr, e3, fmaf(3.f, e1, p6));
                }
            }
        float ps[7] = {p0, p1, p2, p3, p4, p5, p6};
        #pragma unroll
        for (int off = 1; off < 64; off <<= 1)
            #pragma unroll
            for (int t = 0; t < 7; t++) ps[t] += __shfl_xor(ps[t], off, 64);
        if (lane == 0) {
            #pragma unroll
            for (int t = 0; t < 7; t++) atomicAdd(&accum7[t], ps[t]);
        }
    }
    __syncthreads();                                   // S3

    if (tid == 0) {
        const float inv = 1.f / 255.f;
        float vx0 = accum7[0] * inv, vx1 = accum7[1] * inv, vx2 = accum7[2] * inv;
        float cx = (accum7[4] * vx2 - accum7[5] * vx1) * inv;
        float cy = (accum7[5] * vx0 - accum7[3] * vx2) * inv;
        float cz = (accum7[3] * vx1 - accum7[4] * vx0) * inv;
        vx_pre[pi * 4 + 0] = vx0 + cx;
        vx_pre[pi * 4 + 1] = vx1 + cy;
        vx_pre[pi * 4 + 2] = vx2 + cz;
        tr_part[pi] = accum7[6];
    }
    if (tid < 256) {                                   // parallel f second layer
        int f = tid & 31, hg = tid >> 5;
        float p = 0.f;
        #pragma unroll
        for (int t = 0; t < 16; t++) {
            int h = hg * 16 + t;
            p = fmaf(afsumsh[h], f_W2[h * Fn + f], p);
        }
        fpart[hg][f] = p;
    }
    __syncthreads();                                   // S4
    if (tid < Fn) {
        float acc = 0.f;
        #pragma unroll
        for (int g = 0; g < 8; g++) acc += fpart[g][tid];
        out[b * ROW + Nn * 3 + i * Fn + tid] = fmaf(acc, 1.f / 255.f, f_b2[tid]);
    }

    // ---- last-block finalize (remove_mean + trace) ----
    __threadfence();
    __syncthreads();                                   // S5
    if (tid == 0) {
        unsigned int t = atomicAdd(done, 1u);
        lastflag = (t == NPAIR - 1) ? 1u : 0u;
    }
    __syncthreads();                                   // S6
    if (lastflag) {
        __threadfence();
        int bb = w;                                    // wave <-> batch
        float s0 = 0.f, s1 = 0.f, s2 = 0.f, s3 = 0.f;
        for (int ii = lane; ii < Nn; ii += 64) {
            int p = bb * Nn + ii;
            s0 += vx_pre[p * 4 + 0];
            s1 += vx_pre[p * 4 + 1];
            s2 += vx_pre[p * 4 + 2];
            s3 += tr_part[p];
        }
        #pragma unroll
        for (int off = 1; off < 64; off <<= 1) {
            s0 += __shfl_xor(s0, off, 64);
            s1 += __shfl_xor(s1, off, 64);
            s2 += __shfl_xor(s2, off, 64);
            s3 += __shfl_xor(s3, off, 64);
        }
        float m0 = s0 * (1.f / 256.f), m1 = s1 * (1.f / 256.f), m2 = s2 * (1.f / 256.f);
        for (int ii = lane; ii < Nn; ii += 64) {
            int p = bb * Nn + ii;
            out[bb * ROW + ii * 3 + 0] = vx_pre[p * 4 + 0] - m0;
            out[bb * ROW + ii * 3 + 1] = vx_pre[p * 4 + 1] - m1;
            out[bb * ROW + ii * 3 + 2] = vx_pre[p * 4 + 2] - m2;
        }
        if (lane == 0) out[Bn * ROW + bb] = s3 * (1.f / 255.f);
    }
}

// ---------------------------------------------------------------------------
extern "C" void kernel_launch(void* const* d_in, const int* in_sizes, int n_in,
                              void* d_out, int out_size, void* d_ws, size_t ws_size,
                              hipStream_t stream)
{
    const float* state = (const float*)d_in[1];
    const float* mus   = (const float*)d_in[2];
    const float* gam   = (const float*)d_in[3];
    const float* s1_W1 = (const float*)d_in[4];
    const float* s1_b1 = (const float*)d_in[5];
    const float* s1_W2 = (const float*)d_in[6];
    const float* s1_b2 = (const float*)d_in[7];
    const float* s2_W1 = (const float*)d_in[8];
    const float* s2_b1 = (const float*)d_in[9];
    const float* s2_W2 = (const float*)d_in[10];
    const float* s2_b2 = (const float*)d_in[11];
    const float* f_W1  = (const float*)d_in[12];
    const float* f_b1  = (const float*)d_in[13];
    const float* f_W2  = (const float*)d_in[14];
    const float* f_b2  = (const float*)d_in[15];

    char* wsb = (char*)d_ws;
    __bf16* Wb     = (__bf16*)wsb;                     // 65,536 B
    float*  vx_pre = (float*)(wsb + 65536);            // 32,768 B
    float*  tr_part = vx_pre + NPAIR * 4;              //  8,192 B
    unsigned int* done = (unsigned int*)(wsb + 65536 + 32768 + 8192);
    float*  out    = (float*)d_out;

    prep_kernel<<<128, 256, 0, stream>>>(s1_W1, s2_W1, f_W1, mus, Wb, done);

    dim3 grid(Nn, Bn);
    pair_kernel<<<grid, 512, 0, stream>>>(state, mus, gam,
        s1_W1, s1_b1, s1_W2, s1_b2,
        s2_W1, s2_b1, s2_W2, s2_b2,
        f_W1, f_b1, f_W2, f_b2,
        Wb, vx_pre, tr_part, done, out);
}

// Round 9
// 405.204 us; speedup vs baseline: 2.3512x; 1.1925x over previous
//
#include <hip/hip_runtime.h>
#include <math.h>

#define Bn 8
#define Nn 256
#define Fn 32
#define NRBF 50
#define Hn 128
#define NK 255            // N-1 neighbors
#define ROW 8960          // N*(D+F)
#define EPSf 1e-6f
#define KP 64             // K padded 50 -> 64
#define L2E 1.44269504f
#define NPAIR 2048

typedef __attribute__((ext_vector_type(8))) __bf16 b8;
typedef __attribute__((ext_vector_type(4))) float f32x4;

__device__ __forceinline__ float fast_sig(float z) {
    return __builtin_amdgcn_rcpf(1.f + __builtin_amdgcn_exp2f(-z * L2E));
}

// A-tile XOR swizzle: 16B chunk `ch` of row r lives at elem offset ((ch ^ (r&7))*8)
__device__ __forceinline__ int aswz(int row, int ch) {
    return row * KP + ((ch ^ (row & 7)) << 3);
}

// ---------------------------------------------------------------------------
// Prep: pack Wb[g][h][k] bf16 (g: 0=s1_W1, 1=s1_W1*mu, 2=s2_W1, 3=f_W1;
// k>=50 zeroed) + zero the completion ticket. 128 blocks x 256.
// ---------------------------------------------------------------------------
__global__ __launch_bounds__(256) void prep_kernel(
    const float* __restrict__ s1_W1, const float* __restrict__ s2_W1,
    const float* __restrict__ f_W1,  const float* __restrict__ mus,
    __bf16* __restrict__ Wb, unsigned int* __restrict__ done)
{
    if (blockIdx.x == 0 && threadIdx.x == 0) *done = 0u;
    int idx = blockIdx.x * 256 + threadIdx.x;     // g*Hn*KP + h*KP + k
    int g = idx >> 13;
    int h = (idx >> 6) & 127;
    int k = idx & 63;
    float v = 0.f;
    if (k < NRBF) {
        if (g == 0)      v = s1_W1[k * Hn + h];
        else if (g == 1) v = s1_W1[k * Hn + h] * mus[k];
        else if (g == 2) v = s2_W1[k * Hn + h];
        else             v = f_W1[k * Hn + h];
    }
    Wb[idx] = (__bf16)v;
}

// ---------------------------------------------------------------------------
// One block (256 thr) per (b,i). R5 structure (LDS A-tile, B from global/L2,
// 3 MFMA passes, distributive fold) + inline z-precompute + last-block
// finalize. (256,3): cap 170 unified VGPR+AGPR -> 3 waves/SIMD; peak live
// ~150. (256,4) spilled hard (R4); (256,2) left 2 waves/SIMD (R5).
// ---------------------------------------------------------------------------
__global__ __launch_bounds__(256, 3) void pair_kernel(
    const float* __restrict__ state,
    const float* __restrict__ mus,   const float* __restrict__ gammap,
    const float* __restrict__ s1_W1, const float* __restrict__ s1_b1,
    const float* __restrict__ s1_W2, const float* __restrict__ s1_b2,
    const float* __restrict__ s2_W1, const float* __restrict__ s2_b1,
    const float* __restrict__ s2_W2, const float* __restrict__ s2_b2,
    const float* __restrict__ f_W1,  const float* __restrict__ f_b1,
    const float* __restrict__ f_W2,  const float* __restrict__ f_b2,
    const __bf16* __restrict__ Wb,
    float* __restrict__ vx_pre, float* __restrict__ tr_part,
    unsigned int* __restrict__ done,
    float* __restrict__ out)
{
    const int i = blockIdx.x, b = blockIdx.y;
    const int pi = b * Nn + i;
    const int tid  = threadIdx.x;
    const int w    = tid >> 6;
    const int lane = tid & 63;
    const int c    = lane & 15;       // A m-offset, B n, C/D col
    const int q    = lane >> 4;       // quad

    __shared__ __attribute__((aligned(16))) __bf16 As[256 * KP];   // 32 KiB
    __shared__ float xpos[Nn * 3];
    __shared__ float musS[64];
    __shared__ float ff[Fn], sf[Fn];
    __shared__ float zf1s[Hn], zf2s[Hn], zffs[Hn];
    __shared__ float sW2a[Hn], sW2b[Hn];
    __shared__ float afsumsh[Hn];
    __shared__ float accum7[8];
    __shared__ unsigned int lastflag;

    // ---- phase 0: stage; wave-3 shuffle softmax ----
    for (int t = tid; t < Nn * 3; t += 256) xpos[t] = state[b * ROW + t];
    if (tid < 64)  musS[tid] = (tid < NRBF) ? mus[tid] : 0.f;
    if (tid < Hn) { sW2a[tid] = s1_W2[tid]; sW2b[tid] = s2_W2[tid]; afsumsh[tid] = 0.f; }
    if (tid < 8)   accum7[tid] = 0.f;
    if (tid >= 192 && tid < 224) {                    // wave 3, lanes 0..31
        int l = tid - 192;
        float v = state[b * ROW + Nn * 3 + i * Fn + l];
        ff[l] = v;
        float mx = v;
        #pragma unroll
        for (int off = 16; off; off >>= 1) mx = fmaxf(mx, __shfl_xor(mx, off, 32));
        float e = __builtin_amdgcn_exp2f((v - mx) * L2E);
        float s = e;
        #pragma unroll
        for (int off = 16; off; off >>= 1) s += __shfl_xor(s, off, 32);
        sf[l] = e * __builtin_amdgcn_rcpf(s);
    }
    __syncthreads();                                   // S1

    const float gamma = gammap[0];
    const float ngl   = -gamma * L2E;

    // ---- phase 1a: rbf rows -> As (bf16, swizzled) ----
    {
        const float valid = (tid < NK) ? 1.f : 0.f;
        const int   kk    = (tid < NK) ? tid : 0;
        const int   j     = kk + (kk >= i ? 1 : 0);
        float rx = (xpos[i * 3 + 0] - xpos[j * 3 + 0]) * valid;
        float ry = (xpos[i * 3 + 1] - xpos[j * 3 + 1]) * valid;
        float rz = (xpos[i * 3 + 2] - xpos[j * 3 + 2]) * valid;
        float ssq = rx * rx + ry * ry + rz * rz;
        float dd  = sqrtf(ssq + EPSf);
        #pragma unroll
        for (int ch = 0; ch < 8; ch++) {
            b8 v;
            #pragma unroll
            for (int jj = 0; jj < 8; jj++) {
                int m = ch * 8 + jj;
                float t = dd - musS[m];
                float rv = (m < NRBF) ? __builtin_amdgcn_exp2f(ngl * t * t) * valid : 0.f;
                v[jj] = (__bf16)rv;
            }
            *(b8*)&As[aswz(tid, ch)] = v;
        }
    }

    // ---- phase 1b: inline k-independent layer-1 halves ----
    if (tid < Hn) {
        int h = tid;
        float z1 = s1_b1[h], z2 = s2_b1[h];
        for (int f = 0; f < Fn; f++) {
            float fv = ff[f];
            z1 += fv * (s1_W1[(NRBF + f) * Hn + h] + s1_W1[(NRBF + Fn + f) * Hn + h]);
            z2 += fv * (s2_W1[(NRBF + f) * Hn + h] + s2_W1[(NRBF + Fn + f) * Hn + h]);
        }
        zf1s[h] = z1; zf2s[h] = z2;
    } else {
        int h = tid - Hn;
        float zf = f_b1[h];
        for (int f = 0; f < Fn; f++)
            zf += sf[f] * f_W1[(NRBF + f) * Hn + h];
        zffs[h] = zf;
    }
    __syncthreads();                                   // S2

    const int row0 = w * 64;

    float s1p[16], ds1a[16], ds1b[16], s2p[16];
    #pragma unroll
    for (int t = 0; t < 16; t++) { s1p[t] = 0.f; ds1a[t] = 0.f; ds1b[t] = 0.f; s2p[t] = 0.f; }

    // ---- pass 1: s1 + split derivative ----
    {
        b8 a0[4], a1[4];
        #pragma unroll
        for (int mc = 0; mc < 4; mc++) {
            int rrow = row0 + mc * 16 + c;
            a0[mc] = *(const b8*)&As[aswz(rrow, q)];
            a1[mc] = *(const b8*)&As[aswz(rrow, 4 + q)];
        }
        for (int nt = 0; nt < 8; nt++) {
            int h = nt * 16 + c;
            const b8* B0 = (const b8*)&Wb[(0 * Hn + h) * KP];
            const b8* B1 = (const b8*)&Wb[(1 * Hn + h) * KP];
            b8 b00 = B0[q], b01 = B0[4 + q];
            b8 b10 = B1[q], b11 = B1[4 + q];
            float w2  = sW2a[h];
            float zf1 = zf1s[h];
            #pragma unroll
            for (int mc = 0; mc < 4; mc++) {
                f32x4 acc1 = {0.f, 0.f, 0.f, 0.f}, accm = {0.f, 0.f, 0.f, 0.f};
                acc1 = __builtin_amdgcn_mfma_f32_16x16x32_bf16(a0[mc], b00, acc1, 0, 0, 0);
                acc1 = __builtin_amdgcn_mfma_f32_16x16x32_bf16(a1[mc], b01, acc1, 0, 0, 0);
                accm = __builtin_amdgcn_mfma_f32_16x16x32_bf16(a0[mc], b10, accm, 0, 0, 0);
                accm = __builtin_amdgcn_mfma_f32_16x16x32_bf16(a1[mc], b11, accm, 0, 0, 0);
                #pragma unroll
                for (int r = 0; r < 4; r++) {
                    int idx = mc * 4 + r;
                    float zr1 = acc1[r];
                    float z1  = zr1 + zf1;
                    float sig = fast_sig(z1);
                    s1p[idx]  = fmaf(z1 * sig, w2, s1p[idx]);
                    float cc  = w2 * (sig * fmaf(z1, 1.f - sig, 1.f));
                    ds1a[idx] = fmaf(cc, zr1, ds1a[idx]);
                    ds1b[idx] = fmaf(cc, accm[r], ds1b[idx]);
                }
            }
        }
    }

    // ---- pass 2: s2 ----
    {
        b8 a0[4], a1[4];
        #pragma unroll
        for (int mc = 0; mc < 4; mc++) {
            int rrow = row0 + mc * 16 + c;
            a0[mc] = *(const b8*)&As[aswz(rrow, q)];
            a1[mc] = *(const b8*)&As[aswz(rrow, 4 + q)];
        }
        for (int nt = 0; nt < 8; nt++) {
            int h = nt * 16 + c;
            const b8* B2 = (const b8*)&Wb[(2 * Hn + h) * KP];
            b8 b20 = B2[q], b21 = B2[4 + q];
            float w2  = sW2b[h];
            float zf2 = zf2s[h];
            #pragma unroll
            for (int mc = 0; mc < 4; mc++) {
                f32x4 acc = {0.f, 0.f, 0.f, 0.f};
                acc = __builtin_amdgcn_mfma_f32_16x16x32_bf16(a0[mc], b20, acc, 0, 0, 0);
                acc = __builtin_amdgcn_mfma_f32_16x16x32_bf16(a1[mc], b21, acc, 0, 0, 0);
                #pragma unroll
                for (int r = 0; r < 4; r++) {
                    int idx = mc * 4 + r;
                    float z2 = acc[r] + zf2;
                    s2p[idx] = fmaf(z2 * fast_sig(z2), w2, s2p[idx]);
                }
            }
        }
    }

    // ---- pass 3: f MLP hidden, reduce over rows ----
    {
        b8 a0[4], a1[4];
        #pragma unroll
        for (int mc = 0; mc < 4; mc++) {
            int rrow = row0 + mc * 16 + c;
            a0[mc] = *(const b8*)&As[aswz(rrow, q)];
            a1[mc] = *(const b8*)&As[aswz(rrow, 4 + q)];
        }
        for (int nt = 0; nt < 8; nt++) {
            int h = nt * 16 + c;
            const b8* B3 = (const b8*)&Wb[(3 * Hn + h) * KP];
            b8 b30 = B3[q], b31 = B3[4 + q];
            float zff = zffs[h];
            float afp = 0.f;
            #pragma unroll
            for (int mc = 0; mc < 4; mc++) {
                f32x4 acc = {0.f, 0.f, 0.f, 0.f};
                acc = __builtin_amdgcn_mfma_f32_16x16x32_bf16(a0[mc], b30, acc, 0, 0, 0);
                acc = __builtin_amdgcn_mfma_f32_16x16x32_bf16(a1[mc], b31, acc, 0, 0, 0);
                #pragma unroll
                for (int r = 0; r < 4; r++) {
                    int row = row0 + mc * 16 + q * 4 + r;
                    float z  = acc[r] + zff;
                    float av = z * fast_sig(z);
                    afp += (row < NK) ? av : 0.f;
                }
            }
            afp += __shfl_xor(afp, 16, 64);
            afp += __shfl_xor(afp, 32, 64);
            if (lane < 16) atomicAdd(&afsumsh[h], afp);
        }
    }

    // ---- distributive fold over this wave's 16 rows/lane ----
    {
        const float b2_1 = (c == 0) ? s1_b2[0] : 0.f;
        const float b2_2 = (c == 0) ? s2_b2[0] : 0.f;
        const float n2g  = -2.f * gamma;
        const float xi0 = xpos[i * 3 + 0], xi1 = xpos[i * 3 + 1], xi2 = xpos[i * 3 + 2];
        float p0 = 0.f, p1 = 0.f, p2 = 0.f, p3 = 0.f, p4 = 0.f, p5 = 0.f, p6 = 0.f;
        #pragma unroll
        for (int mc = 0; mc < 4; mc++)
            #pragma unroll
            for (int r = 0; r < 4; r++) {
                int idx = mc * 4 + r;
                int row = row0 + mc * 16 + q * 4 + r;
                if (row < NK) {
                    int j = row + (row >= i ? 1 : 0);
                    float rx = xi0 - xpos[j * 3 + 0];
                    float ry = xi1 - xpos[j * 3 + 1];
                    float rz = xi2 - xpos[j * 3 + 2];
                    float ssq = rx * rx + ry * ry + rz * rz;
                    float se  = ssq + EPSf;
                    float it  = __builtin_amdgcn_rsqf(se);
                    float dd  = se * it;
                    float e1  = s1p[idx] + b2_1;
                    float e2  = s2p[idx] + b2_2;
                    float e3  = fmaf(dd, ds1a[idx], -ds1b[idx]);
                    float fr  = n2g * ssq * it;
                    p0 = fmaf(rx, e1, p0); p1 = fmaf(ry, e1, p1); p2 = fmaf(rz, e1, p2);
                    p3 = fmaf(rx, e2, p3); p4 = fmaf(ry, e2, p4); p5 = fmaf(rz, e2, p5);
                    p6 = fmaf(fr, e3, fmaf(3.f, e1, p6));
                }
            }
        float ps[7] = {p0, p1, p2, p3, p4, p5, p6};
        #pragma unroll
        for (int off = 1; off < 64; off <<= 1)
            #pragma unroll
            for (int t = 0; t < 7; t++) ps[t] += __shfl_xor(ps[t], off, 64);
        if (lane == 0) {
            #pragma unroll
            for (int t = 0; t < 7; t++) atomicAdd(&accum7[t], ps[t]);
        }
    }
    __syncthreads();                                   // S3

    if (tid == 0) {
        const float inv = 1.f / 255.f;
        float vx0 = accum7[0] * inv, vx1 = accum7[1] * inv, vx2 = accum7[2] * inv;
        float cx = (accum7[4] * vx2 - accum7[5] * vx1) * inv;
        float cy = (accum7[5] * vx0 - accum7[3] * vx2) * inv;
        float cz = (accum7[3] * vx1 - accum7[4] * vx0) * inv;
        vx_pre[pi * 4 + 0] = vx0 + cx;
        vx_pre[pi * 4 + 1] = vx1 + cy;
        vx_pre[pi * 4 + 2] = vx2 + cz;
        tr_part[pi] = accum7[6];
    }
    if (tid < Fn) {
        float acc = 0.f;
        for (int h = 0; h < Hn; h++) acc = fmaf(afsumsh[h], f_W2[h * Fn + tid], acc);
        out[b * ROW + Nn * 3 + i * Fn + tid] = fmaf(acc, 1.f / 255.f, f_b2[tid]);
    }

    // ---- last-block finalize (remove_mean + trace) ----
    __threadfence();
    __syncthreads();                                   // S4
    if (tid == 0) {
        unsigned int t = atomicAdd(done, 1u);
        lastflag = (t == NPAIR - 1) ? 1u : 0u;
    }
    __syncthreads();                                   // S5
    if (lastflag) {
        __threadfence();
        for (int bb = w; bb < Bn; bb += 4) {          // 4 waves x 2 batches
            float s0 = 0.f, s1 = 0.f, s2 = 0.f, s3 = 0.f;
            for (int ii = lane; ii < Nn; ii += 64) {
                int p = bb * Nn + ii;
                s0 += vx_pre[p * 4 + 0];
                s1 += vx_pre[p * 4 + 1];
                s2 += vx_pre[p * 4 + 2];
                s3 += tr_part[p];
            }
            #pragma unroll
            for (int off = 1; off < 64; off <<= 1) {
                s0 += __shfl_xor(s0, off, 64);
                s1 += __shfl_xor(s1, off, 64);
                s2 += __shfl_xor(s2, off, 64);
                s3 += __shfl_xor(s3, off, 64);
            }
            float m0 = s0 * (1.f / 256.f), m1 = s1 * (1.f / 256.f), m2 = s2 * (1.f / 256.f);
            for (int ii = lane; ii < Nn; ii += 64) {
                int p = bb * Nn + ii;
                out[bb * ROW + ii * 3 + 0] = vx_pre[p * 4 + 0] - m0;
                out[bb * ROW + ii * 3 + 1] = vx_pre[p * 4 + 1] - m1;
                out[bb * ROW + ii * 3 + 2] = vx_pre[p * 4 + 2] - m2;
            }
            if (lane == 0) out[Bn * ROW + bb] = s3 * (1.f / 255.f);
        }
    }
}

// ---------------------------------------------------------------------------
extern "C" void kernel_launch(void* const* d_in, const int* in_sizes, int n_in,
                              void* d_out, int out_size, void* d_ws, size_t ws_size,
                              hipStream_t stream)
{
    const float* state = (const float*)d_in[1];
    const float* mus   = (const float*)d_in[2];
    const float* gam   = (const float*)d_in[3];
    const float* s1_W1 = (const float*)d_in[4];
    const float* s1_b1 = (const float*)d_in[5];
    const float* s1_W2 = (const float*)d_in[6];
    const float* s1_b2 = (const float*)d_in[7];
    const float* s2_W1 = (const float*)d_in[8];
    const float* s2_b1 = (const float*)d_in[9];
    const float* s2_W2 = (const float*)d_in[10];
    const float* s2_b2 = (const float*)d_in[11];
    const float* f_W1  = (const float*)d_in[12];
    const float* f_b1  = (const float*)d_in[13];
    const float* f_W2  = (const float*)d_in[14];
    const float* f_b2  = (const float*)d_in[15];

    char* wsb = (char*)d_ws;
    __bf16* Wb     = (__bf16*)wsb;                     // 65,536 B
    float*  vx_pre = (float*)(wsb + 65536);            // 32,768 B
    float*  tr_part = vx_pre + NPAIR * 4;              //  8,192 B
    unsigned int* done = (unsigned int*)(wsb + 65536 + 32768 + 8192);
    float*  out    = (float*)d_out;

    prep_kernel<<<128, 256, 0, stream>>>(s1_W1, s2_W1, f_W1, mus, Wb, done);

    dim3 grid(Nn, Bn);
    pair_kernel<<<grid, 256, 0, stream>>>(state, mus, gam,
        s1_W1, s1_b1, s1_W2, s1_b2,
        s2_W1, s2_b1, s2_W2, s2_b2,
        f_W1, f_b1, f_W2, f_b2,
        Wb, vx_pre, tr_part, done, out);
}

// Round 10
// 315.085 us; speedup vs baseline: 3.0237x; 1.2860x over previous
//
#include <hip/hip_runtime.h>
#include <math.h>

#define Bn 8
#define Nn 256
#define Fn 32
#define NRBF 50
#define Hn 128
#define NK 255            // N-1 neighbors
#define ROW 8960          // N*(D+F)
#define EPSf 1e-6f
#define KP 64             // K padded 50 -> 64
#define L2E 1.44269504f
#define NPAIR 2048

typedef __attribute__((ext_vector_type(8))) __bf16 b8;
typedef __attribute__((ext_vector_type(4))) float f32x4;

__device__ __forceinline__ float fast_sig(float z) {
    return __builtin_amdgcn_rcpf(1.f + __builtin_amdgcn_exp2f(-z * L2E));
}

// A-tile XOR swizzle: 16B chunk `ch` of row r lives at elem offset ((ch ^ (r&7))*8)
__device__ __forceinline__ int aswz(int row, int ch) {
    return row * KP + ((ch ^ (row & 7)) << 3);
}

// ---------------------------------------------------------------------------
// Prep: pack Wb[g][h][k] bf16 (g: 0=s1_W1, 1=s1_W1*mu, 2=s2_W1, 3=f_W1;
// k>=50 zeroed) + zero the completion ticket. 128 blocks x 256.
// ---------------------------------------------------------------------------
__global__ __launch_bounds__(256) void prep_kernel(
    const float* __restrict__ s1_W1, const float* __restrict__ s2_W1,
    const float* __restrict__ f_W1,  const float* __restrict__ mus,
    __bf16* __restrict__ Wb, unsigned int* __restrict__ done)
{
    if (blockIdx.x == 0 && threadIdx.x == 0) *done = 0u;
    int idx = blockIdx.x * 256 + threadIdx.x;     // g*Hn*KP + h*KP + k
    int g = idx >> 13;
    int h = (idx >> 6) & 127;
    int k = idx & 63;
    float v = 0.f;
    if (k < NRBF) {
        if (g == 0)      v = s1_W1[k * Hn + h];
        else if (g == 1) v = s1_W1[k * Hn + h] * mus[k];
        else if (g == 2) v = s2_W1[k * Hn + h];
        else             v = f_W1[k * Hn + h];
    }
    Wb[idx] = (__bf16)v;
}

// ---------------------------------------------------------------------------
// One block (256 thr) per (b,i). R5 structure (LDS A-tile, B from global/L2,
// 3 MFMA passes, distributive fold) + inline z-precompute + last-block
// finalize. (256,2) ONLY: peak live state ~175 unified VGPR+AGPR; every
// higher waves/EU bound spilled (R4: 500MB, R7: 1.4GB, R9: 300MB scratch).
// ---------------------------------------------------------------------------
__global__ __launch_bounds__(256, 2) void pair_kernel(
    const float* __restrict__ state,
    const float* __restrict__ mus,   const float* __restrict__ gammap,
    const float* __restrict__ s1_W1, const float* __restrict__ s1_b1,
    const float* __restrict__ s1_W2, const float* __restrict__ s1_b2,
    const float* __restrict__ s2_W1, const float* __restrict__ s2_b1,
    const float* __restrict__ s2_W2, const float* __restrict__ s2_b2,
    const float* __restrict__ f_W1,  const float* __restrict__ f_b1,
    const float* __restrict__ f_W2,  const float* __restrict__ f_b2,
    const __bf16* __restrict__ Wb,
    float* __restrict__ vx_pre, float* __restrict__ tr_part,
    unsigned int* __restrict__ done,
    float* __restrict__ out)
{
    const int i = blockIdx.x, b = blockIdx.y;
    const int pi = b * Nn + i;
    const int tid  = threadIdx.x;
    const int w    = tid >> 6;
    const int lane = tid & 63;
    const int c    = lane & 15;       // A m-offset, B n, C/D col
    const int q    = lane >> 4;       // quad

    __shared__ __attribute__((aligned(16))) __bf16 As[256 * KP];   // 32 KiB
    __shared__ float xpos[Nn * 3];
    __shared__ float musS[64];
    __shared__ float ff[Fn], sf[Fn];
    __shared__ float zf1s[Hn], zf2s[Hn], zffs[Hn];
    __shared__ float sW2a[Hn], sW2b[Hn];
    __shared__ float afsumsh[Hn];
    __shared__ float accum7[8];
    __shared__ unsigned int lastflag;

    // ---- phase 0: stage; wave-3 shuffle softmax ----
    for (int t = tid; t < Nn * 3; t += 256) xpos[t] = state[b * ROW + t];
    if (tid < 64)  musS[tid] = (tid < NRBF) ? mus[tid] : 0.f;
    if (tid < Hn) { sW2a[tid] = s1_W2[tid]; sW2b[tid] = s2_W2[tid]; afsumsh[tid] = 0.f; }
    if (tid < 8)   accum7[tid] = 0.f;
    if (tid >= 192 && tid < 224) {                    // wave 3, lanes 0..31
        int l = tid - 192;
        float v = state[b * ROW + Nn * 3 + i * Fn + l];
        ff[l] = v;
        float mx = v;
        #pragma unroll
        for (int off = 16; off; off >>= 1) mx = fmaxf(mx, __shfl_xor(mx, off, 32));
        float e = __builtin_amdgcn_exp2f((v - mx) * L2E);
        float s = e;
        #pragma unroll
        for (int off = 16; off; off >>= 1) s += __shfl_xor(s, off, 32);
        sf[l] = e * __builtin_amdgcn_rcpf(s);
    }
    __syncthreads();                                   // S1

    const float gamma = gammap[0];
    const float ngl   = -gamma * L2E;

    // ---- phase 1a: rbf rows -> As (bf16, swizzled) ----
    {
        const float valid = (tid < NK) ? 1.f : 0.f;
        const int   kk    = (tid < NK) ? tid : 0;
        const int   j     = kk + (kk >= i ? 1 : 0);
        float rx = (xpos[i * 3 + 0] - xpos[j * 3 + 0]) * valid;
        float ry = (xpos[i * 3 + 1] - xpos[j * 3 + 1]) * valid;
        float rz = (xpos[i * 3 + 2] - xpos[j * 3 + 2]) * valid;
        float ssq = rx * rx + ry * ry + rz * rz;
        float dd  = sqrtf(ssq + EPSf);
        #pragma unroll
        for (int ch = 0; ch < 8; ch++) {
            b8 v;
            #pragma unroll
            for (int jj = 0; jj < 8; jj++) {
                int m = ch * 8 + jj;
                float t = dd - musS[m];
                float rv = (m < NRBF) ? __builtin_amdgcn_exp2f(ngl * t * t) * valid : 0.f;
                v[jj] = (__bf16)rv;
            }
            *(b8*)&As[aswz(tid, ch)] = v;
        }
    }

    // ---- phase 1b: inline k-independent layer-1 halves ----
    if (tid < Hn) {
        int h = tid;
        float z1 = s1_b1[h], z2 = s2_b1[h];
        for (int f = 0; f < Fn; f++) {
            float fv = ff[f];
            z1 += fv * (s1_W1[(NRBF + f) * Hn + h] + s1_W1[(NRBF + Fn + f) * Hn + h]);
            z2 += fv * (s2_W1[(NRBF + f) * Hn + h] + s2_W1[(NRBF + Fn + f) * Hn + h]);
        }
        zf1s[h] = z1; zf2s[h] = z2;
    } else {
        int h = tid - Hn;
        float zf = f_b1[h];
        for (int f = 0; f < Fn; f++)
            zf += sf[f] * f_W1[(NRBF + f) * Hn + h];
        zffs[h] = zf;
    }
    __syncthreads();                                   // S2

    const int row0 = w * 64;

    float s1p[16], ds1a[16], ds1b[16], s2p[16];
    #pragma unroll
    for (int t = 0; t < 16; t++) { s1p[t] = 0.f; ds1a[t] = 0.f; ds1b[t] = 0.f; s2p[t] = 0.f; }

    // ---- pass 1: s1 + split derivative ----
    {
        b8 a0[4], a1[4];
        #pragma unroll
        for (int mc = 0; mc < 4; mc++) {
            int rrow = row0 + mc * 16 + c;
            a0[mc] = *(const b8*)&As[aswz(rrow, q)];
            a1[mc] = *(const b8*)&As[aswz(rrow, 4 + q)];
        }
        for (int nt = 0; nt < 8; nt++) {
            int h = nt * 16 + c;
            const b8* B0 = (const b8*)&Wb[(0 * Hn + h) * KP];
            const b8* B1 = (const b8*)&Wb[(1 * Hn + h) * KP];
            b8 b00 = B0[q], b01 = B0[4 + q];
            b8 b10 = B1[q], b11 = B1[4 + q];
            float w2  = sW2a[h];
            float zf1 = zf1s[h];
            #pragma unroll
            for (int mc = 0; mc < 4; mc++) {
                f32x4 acc1 = {0.f, 0.f, 0.f, 0.f}, accm = {0.f, 0.f, 0.f, 0.f};
                acc1 = __builtin_amdgcn_mfma_f32_16x16x32_bf16(a0[mc], b00, acc1, 0, 0, 0);
                acc1 = __builtin_amdgcn_mfma_f32_16x16x32_bf16(a1[mc], b01, acc1, 0, 0, 0);
                accm = __builtin_amdgcn_mfma_f32_16x16x32_bf16(a0[mc], b10, accm, 0, 0, 0);
                accm = __builtin_amdgcn_mfma_f32_16x16x32_bf16(a1[mc], b11, accm, 0, 0, 0);
                #pragma unroll
                for (int r = 0; r < 4; r++) {
                    int idx = mc * 4 + r;
                    float zr1 = acc1[r];
                    float z1  = zr1 + zf1;
                    float sig = fast_sig(z1);
                    s1p[idx]  = fmaf(z1 * sig, w2, s1p[idx]);
                    float cc  = w2 * (sig * fmaf(z1, 1.f - sig, 1.f));
                    ds1a[idx] = fmaf(cc, zr1, ds1a[idx]);
                    ds1b[idx] = fmaf(cc, accm[r], ds1b[idx]);
                }
            }
        }
    }

    // ---- pass 2: s2 ----
    {
        b8 a0[4], a1[4];
        #pragma unroll
        for (int mc = 0; mc < 4; mc++) {
            int rrow = row0 + mc * 16 + c;
            a0[mc] = *(const b8*)&As[aswz(rrow, q)];
            a1[mc] = *(const b8*)&As[aswz(rrow, 4 + q)];
        }
        for (int nt = 0; nt < 8; nt++) {
            int h = nt * 16 + c;
            const b8* B2 = (const b8*)&Wb[(2 * Hn + h) * KP];
            b8 b20 = B2[q], b21 = B2[4 + q];
            float w2  = sW2b[h];
            float zf2 = zf2s[h];
            #pragma unroll
            for (int mc = 0; mc < 4; mc++) {
                f32x4 acc = {0.f, 0.f, 0.f, 0.f};
                acc = __builtin_amdgcn_mfma_f32_16x16x32_bf16(a0[mc], b20, acc, 0, 0, 0);
                acc = __builtin_amdgcn_mfma_f32_16x16x32_bf16(a1[mc], b21, acc, 0, 0, 0);
                #pragma unroll
                for (int r = 0; r < 4; r++) {
                    int idx = mc * 4 + r;
                    float z2 = acc[r] + zf2;
                    s2p[idx] = fmaf(z2 * fast_sig(z2), w2, s2p[idx]);
                }
            }
        }
    }

    // ---- pass 3: f MLP hidden, reduce over rows ----
    {
        b8 a0[4], a1[4];
        #pragma unroll
        for (int mc = 0; mc < 4; mc++) {
            int rrow = row0 + mc * 16 + c;
            a0[mc] = *(const b8*)&As[aswz(rrow, q)];
            a1[mc] = *(const b8*)&As[aswz(rrow, 4 + q)];
        }
        for (int nt = 0; nt < 8; nt++) {
            int h = nt * 16 + c;
            const b8* B3 = (const b8*)&Wb[(3 * Hn + h) * KP];
            b8 b30 = B3[q], b31 = B3[4 + q];
            float zff = zffs[h];
            float afp = 0.f;
            #pragma unroll
            for (int mc = 0; mc < 4; mc++) {
                f32x4 acc = {0.f, 0.f, 0.f, 0.f};
                acc = __builtin_amdgcn_mfma_f32_16x16x32_bf16(a0[mc], b30, acc, 0, 0, 0);
                acc = __builtin_amdgcn_mfma_f32_16x16x32_bf16(a1[mc], b31, acc, 0, 0, 0);
                #pragma unroll
                for (int r = 0; r < 4; r++) {
                    int row = row0 + mc * 16 + q * 4 + r;
                    float z  = acc[r] + zff;
                    float av = z * fast_sig(z);
                    afp += (row < NK) ? av : 0.f;
                }
            }
            afp += __shfl_xor(afp, 16, 64);
            afp += __shfl_xor(afp, 32, 64);
            if (lane < 16) atomicAdd(&afsumsh[h], afp);
        }
    }

    // ---- distributive fold over this wave's 16 rows/lane ----
    {
        const float b2_1 = (c == 0) ? s1_b2[0] : 0.f;
        const float b2_2 = (c == 0) ? s2_b2[0] : 0.f;
        const float n2g  = -2.f * gamma;
        const float xi0 = xpos[i * 3 + 0], xi1 = xpos[i * 3 + 1], xi2 = xpos[i * 3 + 2];
        float p0 = 0.f, p1 = 0.f, p2 = 0.f, p3 = 0.f, p4 = 0.f, p5 = 0.f, p6 = 0.f;
        #pragma unroll
        for (int mc = 0; mc < 4; mc++)
            #pragma unroll
            for (int r = 0; r < 4; r++) {
                int idx = mc * 4 + r;
                int row = row0 + mc * 16 + q * 4 + r;
                if (row < NK) {
                    int j = row + (row >= i ? 1 : 0);
                    float rx = xi0 - xpos[j * 3 + 0];
                    float ry = xi1 - xpos[j * 3 + 1];
                    float rz = xi2 - xpos[j * 3 + 2];
                    float ssq = rx * rx + ry * ry + rz * rz;
                    float se  = ssq + EPSf;
                    float it  = __builtin_amdgcn_rsqf(se);
                    float dd  = se * it;
                    float e1  = s1p[idx] + b2_1;
                    float e2  = s2p[idx] + b2_2;
                    float e3  = fmaf(dd, ds1a[idx], -ds1b[idx]);
                    float fr  = n2g * ssq * it;
                    p0 = fmaf(rx, e1, p0); p1 = fmaf(ry, e1, p1); p2 = fmaf(rz, e1, p2);
                    p3 = fmaf(rx, e2, p3); p4 = fmaf(ry, e2, p4); p5 = fmaf(rz, e2, p5);
                    p6 = fmaf(fr, e3, fmaf(3.f, e1, p6));
                }
            }
        float ps[7] = {p0, p1, p2, p3, p4, p5, p6};
        #pragma unroll
        for (int off = 1; off < 64; off <<= 1)
            #pragma unroll
            for (int t = 0; t < 7; t++) ps[t] += __shfl_xor(ps[t], off, 64);
        if (lane == 0) {
            #pragma unroll
            for (int t = 0; t < 7; t++) atomicAdd(&accum7[t], ps[t]);
        }
    }
    __syncthreads();                                   // S3

    if (tid == 0) {
        const float inv = 1.f / 255.f;
        float vx0 = accum7[0] * inv, vx1 = accum7[1] * inv, vx2 = accum7[2] * inv;
        float cx = (accum7[4] * vx2 - accum7[5] * vx1) * inv;
        float cy = (accum7[5] * vx0 - accum7[3] * vx2) * inv;
        float cz = (accum7[3] * vx1 - accum7[4] * vx0) * inv;
        vx_pre[pi * 4 + 0] = vx0 + cx;
        vx_pre[pi * 4 + 1] = vx1 + cy;
        vx_pre[pi * 4 + 2] = vx2 + cz;
        tr_part[pi] = accum7[6];
    }
    if (tid < Fn) {
        float acc = 0.f;
        for (int h = 0; h < Hn; h++) acc = fmaf(afsumsh[h], f_W2[h * Fn + tid], acc);
        out[b * ROW + Nn * 3 + i * Fn + tid] = fmaf(acc, 1.f / 255.f, f_b2[tid]);
    }

    // ---- last-block finalize (remove_mean + trace) ----
    __threadfence();
    __syncthreads();                                   // S4
    if (tid == 0) {
        unsigned int t = atomicAdd(done, 1u);
        lastflag = (t == NPAIR - 1) ? 1u : 0u;
    }
    __syncthreads();                                   // S5
    if (lastflag) {
        __threadfence();
        for (int bb = w; bb < Bn; bb += 4) {          // 4 waves x 2 batches
            float s0 = 0.f, s1 = 0.f, s2 = 0.f, s3 = 0.f;
            for (int ii = lane; ii < Nn; ii += 64) {
                int p = bb * Nn + ii;
                s0 += vx_pre[p * 4 + 0];
                s1 += vx_pre[p * 4 + 1];
                s2 += vx_pre[p * 4 + 2];
                s3 += tr_part[p];
            }
            #pragma unroll
            for (int off = 1; off < 64; off <<= 1) {
                s0 += __shfl_xor(s0, off, 64);
                s1 += __shfl_xor(s1, off, 64);
                s2 += __shfl_xor(s2, off, 64);
                s3 += __shfl_xor(s3, off, 64);
            }
            float m0 = s0 * (1.f / 256.f), m1 = s1 * (1.f / 256.f), m2 = s2 * (1.f / 256.f);
            for (int ii = lane; ii < Nn; ii += 64) {
                int p = bb * Nn + ii;
                out[bb * ROW + ii * 3 + 0] = vx_pre[p * 4 + 0] - m0;
                out[bb * ROW + ii * 3 + 1] = vx_pre[p * 4 + 1] - m1;
                out[bb * ROW + ii * 3 + 2] = vx_pre[p * 4 + 2] - m2;
            }
            if (lane == 0) out[Bn * ROW + bb] = s3 * (1.f / 255.f);
        }
    }
}

// ---------------------------------------------------------------------------
extern "C" void kernel_launch(void* const* d_in, const int* in_sizes, int n_in,
                              void* d_out, int out_size, void* d_ws, size_t ws_size,
                              hipStream_t stream)
{
    const float* state = (const float*)d_in[1];
    const float* mus   = (const float*)d_in[2];
    const float* gam   = (const float*)d_in[3];
    const float* s1_W1 = (const float*)d_in[4];
    const float* s1_b1 = (const float*)d_in[5];
    const float* s1_W2 = (const float*)d_in[6];
    const float* s1_b2 = (const float*)d_in[7];
    const float* s2_W1 = (const float*)d_in[8];
    const float* s2_b1 = (const float*)d_in[9];
    const float* s2_W2 = (const float*)d_in[10];
    const float* s2_b2 = (const float*)d_in[11];
    const float* f_W1  = (const float*)d_in[12];
    const float* f_b1  = (const float*)d_in[13];
    const float* f_W2  = (const float*)d_in[14];
    const float* f_b2  = (const float*)d_in[15];

    char* wsb = (char*)d_ws;
    __bf16* Wb     = (__bf16*)wsb;                     // 65,536 B
    float*  vx_pre = (float*)(wsb + 65536);            // 32,768 B
    float*  tr_part = vx_pre + NPAIR * 4;              //  8,192 B
    unsigned int* done = (unsigned int*)(wsb + 65536 + 32768 + 8192);
    float*  out    = (float*)d_out;

    prep_kernel<<<128, 256, 0, stream>>>(s1_W1, s2_W1, f_W1, mus, Wb, done);

    dim3 grid(Nn, Bn);
    pair_kernel<<<grid, 256, 0, stream>>>(state, mus, gam,
        s1_W1, s1_b1, s1_W2, s1_b2,
        s2_W1, s2_b1, s2_W2, s2_b2,
        f_W1, f_b1, f_W2, f_b2,
        Wb, vx_pre, tr_part, done, out);
}